// Round 2
// baseline (95.263 us; speedup 1.0000x reference)
//
#include <hip/hip_runtime.h>
#include <hip/hip_bf16.h>
#include <stdint.h>

#define HID 128
#define TILE_M 64
#define LDS_PAD 8
#define ROW_STRIDE (HID + LDS_PAD)   // 136 bf16; 272 B row stride; 16B phase shift per row -> only 2-way bank aliasing (free)

typedef __attribute__((ext_vector_type(8))) __bf16 bf16x8;
typedef __attribute__((ext_vector_type(4))) float floatx4;

__device__ inline unsigned short f32_to_bf16_rn(float f) {
    union { float f; unsigned int u; } v; v.f = f;
    unsigned int u = v.u;
    unsigned int r = u + 0x7FFFu + ((u >> 16) & 1u);   // round-to-nearest-even
    return (unsigned short)(r >> 16);
}

__global__ __launch_bounds__(256) void elem_update_kernel(
    const float* __restrict__ h_prev,
    const float* __restrict__ m_curr,
    const int* __restrict__ atom_types,
    const float* __restrict__ weight,
    float* __restrict__ out)
{
    __shared__ unsigned short m_lds[TILE_M * ROW_STRIDE];   // 17408 B
    __shared__ unsigned short w_lds[HID * ROW_STRIDE];      // 34816 B
    __shared__ int types_lds[TILE_M];

    const int tid  = threadIdx.x;
    const int n0   = blockIdx.x * TILE_M;
    const int lane = tid & 63;
    const int wave = tid >> 6;
    const int l15  = lane & 15;
    const int quad = lane >> 4;

    if (tid < TILE_M) types_lds[tid] = atom_types[n0 + tid];

    // stage m tile: 64 rows x 128 fp32 -> bf16 in LDS. 2048 float4-chunks, 8/thread.
    {
        const float4* src = (const float4*)(m_curr + (size_t)n0 * HID);
        #pragma unroll
        for (int it = 0; it < (TILE_M * (HID / 4)) / 256; ++it) {
            int c    = tid + it * 256;
            int row  = c >> 5;        // 32 chunks per row
            int col4 = c & 31;
            float4 v = src[row * (HID / 4) + col4];
            unsigned short b[4] = { f32_to_bf16_rn(v.x), f32_to_bf16_rn(v.y),
                                    f32_to_bf16_rn(v.z), f32_to_bf16_rn(v.w) };
            *(uint2*)(&m_lds[row * ROW_STRIDE + col4 * 4]) = *(const uint2*)b;
        }
    }
    __syncthreads();

    int s = 0;
    while (s < TILE_M) {
        const int z = types_lds[s];
        int e = s + 1;
        while (e < TILE_M && types_lds[e] == z) ++e;   // uniform across block

        // stage W[z]: 128x128 fp32 -> bf16 in LDS. 4096 chunks, 16/thread.
        {
            const float4* wsrc = (const float4*)(weight + (size_t)z * HID * HID);
            #pragma unroll
            for (int it = 0; it < (HID * (HID / 4)) / 256; ++it) {
                int c    = tid + it * 256;
                int row  = c >> 5;
                int col4 = c & 31;
                float4 v = wsrc[row * (HID / 4) + col4];
                unsigned short b[4] = { f32_to_bf16_rn(v.x), f32_to_bf16_rn(v.y),
                                        f32_to_bf16_rn(v.z), f32_to_bf16_rn(v.w) };
                *(uint2*)(&w_lds[row * ROW_STRIDE + col4 * 4]) = *(const uint2*)b;
            }
        }
        __syncthreads();

        // wave w owns M-stripe rows [16w, 16w+16)
        const int r0 = wave * 16;
        if (r0 < e && r0 + 16 > s) {
            floatx4 acc[8];
            #pragma unroll
            for (int nt = 0; nt < 8; ++nt) acc[nt] = (floatx4)(0.0f);

            #pragma unroll
            for (int kk = 0; kk < 4; ++kk) {
                // A-frag: A[m=l15][k = kk*32 + quad*8 + j]  (A = m tile)
                bf16x8 a = *(const bf16x8*)(&m_lds[(r0 + l15) * ROW_STRIDE + kk * 32 + quad * 8]);
                #pragma unroll
                for (int nt = 0; nt < 8; ++nt) {
                    // B-frag: B[k][n=l15] = W[n][k] -> W row (nt*16+l15), k-offset
                    bf16x8 b = *(const bf16x8*)(&w_lds[(nt * 16 + l15) * ROW_STRIDE + kk * 32 + quad * 8]);
                    acc[nt] = __builtin_amdgcn_mfma_f32_16x16x32_bf16(a, b, acc[nt], 0, 0, 0);
                }
            }

            // epilogue: D[row = quad*4 + r][col = nt*16 + l15]; mask rows to [s,e)
            #pragma unroll
            for (int nt = 0; nt < 8; ++nt) {
                #pragma unroll
                for (int r = 0; r < 4; ++r) {
                    int row = r0 + quad * 4 + r;
                    if (row >= s && row < e) {
                        int node = n0 + row;
                        int col  = nt * 16 + l15;
                        size_t idx = (size_t)node * HID + col;
                        out[idx] = h_prev[idx] + acc[nt][r];
                    }
                }
            }
        }
        s = e;
        __syncthreads();   // w_lds safe before next segment staging
    }
}

extern "C" void kernel_launch(void* const* d_in, const int* in_sizes, int n_in,
                              void* d_out, int out_size, void* d_ws, size_t ws_size,
                              hipStream_t stream) {
    const float* h_prev     = (const float*)d_in[0];
    const float* m_curr     = (const float*)d_in[1];
    const int*   atom_types = (const int*)d_in[2];
    const float* weight     = (const float*)d_in[3];
    float*       out        = (float*)d_out;

    const int n_nodes = in_sizes[2];          // 16384
    const int blocks  = n_nodes / TILE_M;     // 256

    elem_update_kernel<<<blocks, 256, 0, stream>>>(h_prev, m_curr, atom_types, weight, out);
}

// Round 3
// 87.068 us; speedup vs baseline: 1.0941x; 1.0941x over previous
//
#include <hip/hip_runtime.h>
#include <hip/hip_bf16.h>
#include <stdint.h>

#define HID 128

typedef __attribute__((ext_vector_type(8))) __bf16 bf16x8;
typedef __attribute__((ext_vector_type(4))) float floatx4;

__device__ inline unsigned short f32_to_bf16_rn(float f) {
    union { float f; unsigned int u; } v; v.f = f;
    unsigned int u = v.u;
    unsigned int r = u + 0x7FFFu + ((u >> 16) & 1u);   // round-to-nearest-even
    return (unsigned short)(r >> 16);
}

// load 8 consecutive fp32 and convert to a bf16x8 fragment (RN)
__device__ inline bf16x8 load_cvt8(const float* __restrict__ p) {
    float4 v0 = *(const float4*)(p);
    float4 v1 = *(const float4*)(p + 4);
    unsigned short b[8] = {
        f32_to_bf16_rn(v0.x), f32_to_bf16_rn(v0.y), f32_to_bf16_rn(v0.z), f32_to_bf16_rn(v0.w),
        f32_to_bf16_rn(v1.x), f32_to_bf16_rn(v1.y), f32_to_bf16_rn(v1.z), f32_to_bf16_rn(v1.w)
    };
    return *(const bf16x8*)b;
}

// One wave owns a 16-row x 32-col output tile. No LDS, no barriers.
// Fragments are read straight from global (fp32) and converted in-register.
__global__ __launch_bounds__(256, 4) void elem_update_kernel(
    const float* __restrict__ h_prev,
    const float* __restrict__ m_curr,
    const int* __restrict__ atom_types,
    const float* __restrict__ weight,
    float* __restrict__ out)
{
    const int tid  = threadIdx.x;
    const int lane = tid & 63;
    const int wave = tid >> 6;
    const int l15  = lane & 15;
    const int quad = lane >> 4;

    const int wg       = blockIdx.x * 4 + wave;  // global wave id
    const int row_tile = wg >> 2;                // 16-row tile index
    const int cq       = wg & 3;                 // column quarter (32 cols)
    const int r0       = row_tile * 16;
    const int c0       = cq * 32;

    // species of this wave's 16 rows (same value pattern in every quad)
    const int t = atom_types[r0 + l15];

    int s = 0;
    while (s < 16) {
        const int z = __shfl(t, s);                       // wave-uniform species
        unsigned long long neq = __ballot(t != z);
        unsigned bits = (unsigned)(neq & 0xFFFFull) & ~((1u << (s + 1)) - 1u);
        const int e = bits ? (int)__builtin_ctz(bits) : 16;   // segment [s,e)

        const float* __restrict__ Wz = weight + (size_t)z * HID * HID;

        // C-init = h_prev at the D-layout positions: row=quad*4+r, col=c0+nt*16+l15
        floatx4 acc[2];
        #pragma unroll
        for (int nt = 0; nt < 2; ++nt) {
            #pragma unroll
            for (int r = 0; r < 4; ++r) {
                acc[nt][r] = h_prev[(size_t)(r0 + quad * 4 + r) * HID + c0 + nt * 16 + l15];
            }
        }

        #pragma unroll
        for (int kk = 0; kk < 4; ++kk) {
            // A-frag: A[m=l15][k=kk*32+quad*8+j] = m_curr row (r0+l15)
            bf16x8 a = load_cvt8(m_curr + (size_t)(r0 + l15) * HID + kk * 32 + quad * 8);
            #pragma unroll
            for (int nt = 0; nt < 2; ++nt) {
                // B-frag: B[k][n=l15] = W[n][k] -> W row (c0+nt*16+l15)
                bf16x8 b = load_cvt8(Wz + (size_t)(c0 + nt * 16 + l15) * HID + kk * 32 + quad * 8);
                acc[nt] = __builtin_amdgcn_mfma_f32_16x16x32_bf16(a, b, acc[nt], 0, 0, 0);
            }
        }

        // epilogue: D[row=quad*4+r][col=c0+nt*16+l15], only rows in [s,e)
        #pragma unroll
        for (int nt = 0; nt < 2; ++nt) {
            #pragma unroll
            for (int r = 0; r < 4; ++r) {
                int row = quad * 4 + r;
                if (row >= s && row < e) {
                    size_t idx = (size_t)(r0 + row) * HID + c0 + nt * 16 + l15;
                    out[idx] = acc[nt][r];
                }
            }
        }
        s = e;
    }
}

extern "C" void kernel_launch(void* const* d_in, const int* in_sizes, int n_in,
                              void* d_out, int out_size, void* d_ws, size_t ws_size,
                              hipStream_t stream) {
    const float* h_prev     = (const float*)d_in[0];
    const float* m_curr     = (const float*)d_in[1];
    const int*   atom_types = (const int*)d_in[2];
    const float* weight     = (const float*)d_in[3];
    float*       out        = (float*)d_out;

    const int n_nodes = in_sizes[2];       // 16384
    const int blocks  = n_nodes / 16;      // 1024 blocks x 4 waves = 4096 waves
    elem_update_kernel<<<blocks, 256, 0, stream>>>(h_prev, m_curr, atom_types, weight, out);
}